// Round 1
// baseline (680.793 us; speedup 1.0000x reference)
//
#include <hip/hip_runtime.h>
#include <hip/hip_bf16.h>
#include <stdint.h>
#include <math.h>

// ZSDPredictor fused kernel set for MI355X (gfx950).
// Plan:
//  k_emb  : per-class projected_emb (pe), ne=l2norm(pe), se_n=l2norm(se), bg=ne@bf
//  k_wcvt : Wcat[768x1024] bf16 = [Wf;Wb;0-pad], stored K-tiled + XOR-swizzled for global_load_lds
//  k_wg   : Wcat rows 624..704 = bf16(ne @ Wf)   (scores folded into main GEMM)
//  k_sim  : S = se_n @ se_n.T (81x81)
//  k_loss : softmax/argsort-free top2/min per row -> margin, distances, mean hinge
//  gemm_main: x(bf16-cvt on the fly) @ Wcat.T, 128x128 tile, BK=64, mfma 16x16x32 bf16.
//             epilogue routes cols: [0,300)->row sumsq partials, [300,624)->bbox+bb,
//             [624,705)->raw_scores+bg, [705,768) pad skip.
//  k_fin  : scores = raw / max(sqrt(p0+p1+p2),1e-12)

typedef __attribute__((ext_vector_type(4))) float        f32x4;
typedef __attribute__((ext_vector_type(8))) short        s16x8;
typedef __attribute__((ext_vector_type(2))) unsigned int u32x2;

#define AS1 __attribute__((address_space(1)))
#define AS3 __attribute__((address_space(3)))

static __device__ __forceinline__ unsigned cvt_pk_bf16(float a, float b) {
    unsigned r;
    asm("v_cvt_pk_bf16_f32 %0, %1, %2" : "=v"(r) : "v"(a), "v"(b));
    return r;
}
static __device__ __forceinline__ unsigned short f2bf(float a) {
    return (unsigned short)(cvt_pk_bf16(a, 0.f) & 0xffffu);
}
static __device__ __forceinline__ void gload_lds16(const void* g, void* l) {
    __builtin_amdgcn_global_load_lds((const AS1 unsigned int*)(uintptr_t)g,
                                     (AS3 unsigned int*)(uintptr_t)l, 16, 0, 0);
}

// ---------------- small kernels ----------------

__global__ __launch_bounds__(256) void k_emb(
    const float* __restrict__ se, const float* __restrict__ We, const float* __restrict__ be,
    const float* __restrict__ bfv,
    float* __restrict__ pe, float* __restrict__ ne, float* __restrict__ sen,
    float* __restrict__ bg)
{
    __shared__ float srow[300];
    __shared__ float red[4];
    const int i = blockIdx.x, tid = threadIdx.x;
    for (int j = tid; j < 300; j += 256) srow[j] = se[i * 300 + j];
    __syncthreads();
    const int j0 = tid, j1 = tid + 256;
    float v0 = 0.f, v1 = 0.f;
    {
        float a = be[j0];
        for (int k = 0; k < 300; k++) a += srow[k] * We[j0 * 300 + k];
        v0 = a; pe[i * 300 + j0] = a;
    }
    if (j1 < 300) {
        float a = be[j1];
        for (int k = 0; k < 300; k++) a += srow[k] * We[j1 * 300 + k];
        v1 = a; pe[i * 300 + j1] = a;
    }
    auto blocksum = [&](float v) -> float {
        for (int o = 1; o < 64; o <<= 1) v += __shfl_xor(v, o);
        __syncthreads();
        if ((tid & 63) == 0) red[tid >> 6] = v;
        __syncthreads();
        return red[0] + red[1] + red[2] + red[3];
    };
    float ss = blocksum(v0 * v0 + v1 * v1);
    float n = fmaxf(sqrtf(ss), 1e-12f);
    ne[i * 300 + j0] = v0 / n;
    if (j1 < 300) ne[i * 300 + j1] = v1 / n;
    float db = blocksum(v0 * bfv[j0] + ((j1 < 300) ? v1 * bfv[j1] : 0.f));
    if (tid == 0) bg[i] = db / n;
    float s0 = srow[j0];
    float s1 = (j1 < 300) ? srow[j1] : 0.f;
    float ss2 = blocksum(s0 * s0 + s1 * s1);
    float n2 = fmaxf(sqrtf(ss2), 1e-12f);
    sen[i * 300 + j0] = s0 / n2;
    if (j1 < 300) sen[i * 300 + j1] = s1 / n2;
}

// swizzled tiled store index for Wcat: tile-step blocks of 128x64 bf16,
// 16B unit t stored at t ^ (row&7)  (matches LDS read-side XOR)
static __device__ __forceinline__ int wcat_idx(int r, int k) {
    int tile = r >> 7, row = r & 127, kt = k >> 6, kc = k & 63;
    int t = ((kc >> 3) ^ (row & 7));
    return ((tile * 16 + kt) * 128 + row) * 64 + t * 8 + (kc & 7);
}

__global__ __launch_bounds__(256) void k_wcvt(
    const float* __restrict__ Wf, const float* __restrict__ Wb, unsigned short* __restrict__ Wcat)
{
    int o = blockIdx.x * 256 + threadIdx.x;  // 0..786431 over 768x1024
    int r = o >> 10, k = o & 1023;
    float v;
    if (r < 300)      v = Wf[r * 1024 + k];
    else if (r < 624) v = Wb[(r - 300) * 1024 + k];
    else if (r < 705) return;                // k_wg fills these
    else              v = 0.f;               // pad rows
    Wcat[wcat_idx(r, k)] = f2bf(v);
}

__global__ __launch_bounds__(256) void k_wg(
    const float* __restrict__ ne, const float* __restrict__ Wf, unsigned short* __restrict__ Wcat)
{
    int o = blockIdx.x * 256 + threadIdx.x;  // 0..82943 over 81x1024
    int j = o >> 10, k = o & 1023;
    const float* nj = ne + j * 300;
    float s = 0.f;
    for (int e = 0; e < 300; e++) s += nj[e] * Wf[e * 1024 + k];
    Wcat[wcat_idx(624 + j, k)] = f2bf(s);
}

__global__ __launch_bounds__(256) void k_sim(const float* __restrict__ sen, float* __restrict__ S)
{
    __shared__ float a[300];
    const int i = blockIdx.x, tid = threadIdx.x;
    for (int j = tid; j < 300; j += 256) a[j] = sen[i * 300 + j];
    __syncthreads();
    if (tid < 81) {
        float s = 0.f;
        const float* b = sen + tid * 300;
        for (int k = 0; k < 300; k++) s += a[k] * b[k];
        S[i * 81 + tid] = s;
    }
}

__global__ __launch_bounds__(128) void k_loss(
    const float* __restrict__ S, const float* __restrict__ pe, float* __restrict__ out)
{
    __shared__ float Sl[81 * 81];
    __shared__ float lred[128];
    const int tid = threadIdx.x;
    for (int idx = tid; idx < 81 * 81; idx += 128) Sl[idx] = S[idx];
    __syncthreads();
    float li = 0.f;
    if (tid < 81) {
        const float* Sr = &Sl[tid * 81];
        float M = -INFINITY;
        for (int j = 0; j < 81; j++) {
            float s = Sr[j];
            float l = (s == 1.0f) ? -INFINITY : s;
            M = fmaxf(M, l);
        }
        float den = 0.f;
        for (int j = 0; j < 81; j++) {
            float s = Sr[j];
            if (s != 1.0f) den += expf(s - M);
        }
        // Sm = mask ? S : softmax ; top-2 (stable: strict >) and min (last on ties: <=)
        float v1 = -INFINITY, v2 = -INFINITY, vmin = INFINITY;
        int i1 = -1, i2 = 0, imin = 0;
        for (int j = 0; j < 81; j++) {
            float s = Sr[j];
            float sm = (s == 1.0f) ? s : (expf(s - M) / den);
            if (sm > v1)      { v2 = v1; i2 = i1; v1 = sm; i1 = j; }
            else if (sm > v2) { v2 = sm; i2 = j; }
            if (sm <= vmin)   { vmin = sm; imin = j; }
        }
        const float* pi = pe + tid * 300;
        const float* pm = pe + i2 * 300;
        const float* pl = pe + imin * 300;
        float dsq = 0.f, ddq = 0.f;
        for (int k = 0; k < 300; k++) {
            float d1 = pi[k] - pm[k]; dsq += d1 * d1;
            float d2 = pi[k] - pl[k]; ddq += d2 * d2;
        }
        li = fmaxf(0.f, sqrtf(dsq) - sqrtf(ddq) + (v2 - vmin));
    }
    lred[tid] = li;
    __syncthreads();
    if (tid == 0) {
        float s = 0.f;
        for (int j = 0; j < 128; j++) s += lred[j];
        out[0] = s / 81.f;
    }
}

// ---------------- main fused GEMM ----------------
// grid 3072 = 8 XCD * 64 strips * 6 ntiles; block 256 (4 waves, 2x2 of 64x64)

__global__ __launch_bounds__(256) void gemm_main(
    const float* __restrict__ x, const unsigned short* __restrict__ Wcat,
    const float* __restrict__ bfv, const float* __restrict__ bbv, const float* __restrict__ bgv,
    float* __restrict__ bbox, float* __restrict__ raw, float* __restrict__ partial)
{
    __shared__ unsigned short Al[128 * 64];
    __shared__ unsigned short Bl[128 * 64];
    __shared__ float redsm[128 * 2];

    const int bid  = blockIdx.x;
    const int xcd  = bid & 7;
    const int ix   = bid >> 3;              // 0..383 within XCD
    const int strip = xcd * 64 + ix / 6;    // 0..511  (M strip of 128 rows)
    const int nt   = ix - (ix / 6) * 6;     // 0..5    (N tile of 128 cols)
    const int tid  = threadIdx.x;
    const int lane = tid & 63;
    const int wid  = tid >> 6;
    const int wm   = wid >> 1, wn = wid & 1;

    // A staging: 8 passes, thread covers row p*16+(tid>>4), 4 floats at col (tid&15)*4
    const int ar0 = tid >> 4;
    const int ac4 = (tid & 15) << 2;
    int aw_byte[8];
    const float* agp[8];
#pragma unroll
    for (int p = 0; p < 8; p++) {
        int r = p * 16 + ar0;
        aw_byte[p] = r * 128 + ((ac4 * 2) ^ ((r & 7) << 4));
        agp[p] = x + (size_t)(strip * 128 + r) * 1024 + ac4;
    }

    // fragment read byte offsets (XOR-swizzled), constant over kt
    int aro[2][4], bro[2][4];
#pragma unroll
    for (int kc = 0; kc < 2; kc++) {
        int kbb = kc * 64 + ((lane >> 4) << 4);
#pragma unroll
        for (int f = 0; f < 4; f++) {
            int ra = wm * 64 + f * 16 + (lane & 15);
            aro[kc][f] = ra * 128 + (kbb ^ ((ra & 7) << 4));
            int rb = wn * 64 + f * 16 + (lane & 15);
            bro[kc][f] = rb * 128 + (kbb ^ ((rb & 7) << 4));
        }
    }

    f32x4 acc[4][4];
#pragma unroll
    for (int i = 0; i < 4; i++)
#pragma unroll
        for (int j = 0; j < 4; j++) acc[i][j] = 0.f;

    const char* wtile = (const char*)Wcat + ((size_t)(nt * 16) << 14);

    for (int kt = 0; kt < 16; ++kt) {
        // B: 16KB tile, pre-swizzled in global -> linear global_load_lds
        {
            const char* gb = wtile + ((size_t)kt << 14) + (wid << 12) + (lane << 4);
            char* lb = (char*)Bl + (wid << 12);
#pragma unroll
            for (int q = 0; q < 4; q++)
                gload_lds16(gb + (q << 10), lb + (q << 10));
        }
        // A: fp32 -> bf16 reg-staged, swizzled ds_write
#pragma unroll
        for (int p = 0; p < 8; p++) {
            f32x4 v = *(const f32x4*)(agp[p] + kt * 64);
            u32x2 h;
            h.x = cvt_pk_bf16(v.x, v.y);
            h.y = cvt_pk_bf16(v.z, v.w);
            *(u32x2*)((char*)Al + aw_byte[p]) = h;
        }
        __syncthreads();
#pragma unroll
        for (int kc = 0; kc < 2; kc++) {
            s16x8 af[4], bfr[4];
#pragma unroll
            for (int f = 0; f < 4; f++) af[f] = *(const s16x8*)((const char*)Al + aro[kc][f]);
#pragma unroll
            for (int f = 0; f < 4; f++) bfr[f] = *(const s16x8*)((const char*)Bl + bro[kc][f]);
#pragma unroll
            for (int m = 0; m < 4; m++)
#pragma unroll
                for (int n = 0; n < 4; n++)
                    acc[m][n] = __builtin_amdgcn_mfma_f32_16x16x32_bf16(af[m], bfr[n], acc[m][n], 0, 0, 0);
        }
        __syncthreads();
    }

    // epilogue: route columns
    const int rbase = strip * 128 + wm * 64 + ((lane >> 4) << 2);
    const int cbase = nt * 128 + wn * 64 + (lane & 15);
    float psq[4][4];
#pragma unroll
    for (int m = 0; m < 4; m++)
#pragma unroll
        for (int i = 0; i < 4; i++) psq[m][i] = 0.f;

#pragma unroll
    for (int m = 0; m < 4; m++) {
#pragma unroll
        for (int n = 0; n < 4; n++) {
            int c = cbase + n * 16;
#pragma unroll
            for (int i = 0; i < 4; i++) {
                int rg = rbase + m * 16 + i;
                float v = acc[m][n][i];
                if (c < 300)      { v += bfv[c]; psq[m][i] += v * v; }
                else if (c < 624) { bbox[rg * 324 + (c - 300)] = v + bbv[c - 300]; }
                else if (c < 705) { raw[rg * 81 + (c - 624)] = v + bgv[c - 624]; }
            }
        }
    }
    if (nt <= 2) {  // tiles containing pv columns -> row sumsq partial
#pragma unroll
        for (int m = 0; m < 4; m++) {
#pragma unroll
            for (int i = 0; i < 4; i++) {
                float s = psq[m][i];
                s += __shfl_xor(s, 1); s += __shfl_xor(s, 2);
                s += __shfl_xor(s, 4); s += __shfl_xor(s, 8);
                if ((lane & 15) == 0) {
                    int rl = wm * 64 + m * 16 + ((lane >> 4) << 2) + i;
                    redsm[rl * 2 + wn] = s;
                }
            }
        }
        __syncthreads();
        if (tid < 128)
            partial[(size_t)(strip * 128 + tid) * 3 + nt] = redsm[tid * 2] + redsm[tid * 2 + 1];
    }
}

__global__ __launch_bounds__(256) void k_fin(
    const float* __restrict__ raw, const float* __restrict__ partial, float* __restrict__ scores)
{
    int o = blockIdx.x * 256 + threadIdx.x;  // exactly 65536*81 threads
    unsigned row = (unsigned)(((unsigned long long)o * 848388602ull) >> 36);  // o/81 exact
    float n2 = partial[row * 3] + partial[row * 3 + 1] + partial[row * 3 + 2];
    float n = fmaxf(sqrtf(n2), 1e-12f);
    scores[o] = raw[o] / n;
}

// ---------------- launcher ----------------

extern "C" void kernel_launch(void* const* d_in, const int* in_sizes, int n_in,
                              void* d_out, int out_size, void* d_ws, size_t ws_size,
                              hipStream_t stream)
{
    (void)in_sizes; (void)n_in; (void)out_size; (void)ws_size;
    const float* x   = (const float*)d_in[0];
    const float* se  = (const float*)d_in[1];
    const float* Wf  = (const float*)d_in[2];
    const float* bfv = (const float*)d_in[3];
    const float* We  = (const float*)d_in[4];
    const float* be  = (const float*)d_in[5];
    const float* Wb  = (const float*)d_in[6];
    const float* bbv = (const float*)d_in[7];

    char* w = (char*)d_ws;                           // ws layout (needs ~23.9 MB)
    unsigned short* Wcat = (unsigned short*)(w);     // 768*1024 bf16 = 1572864 B
    float* raw     = (float*)(w + 1572864);          // 65536*81*4  = 21233664 B
    float* partial = (float*)(w + 22806528);         // 65536*3*4   = 786432 B
    float* pe      = (float*)(w + 23592960);         // 81*300*4
    float* ne      = (float*)(w + 23690160);
    float* sen     = (float*)(w + 23787360);
    float* S       = (float*)(w + 23884560);         // 81*81*4
    float* bg      = (float*)(w + 23910804);         // 81*4

    float* scores = (float*)d_out;                   // 65536*81
    float* bbox   = scores + 5308416;                // 65536*324
    float* lossp  = scores + 26542080;               // scalar

    hipLaunchKernelGGL(k_emb,  dim3(81),    dim3(256), 0, stream, se, We, be, bfv, pe, ne, sen, bg);
    hipLaunchKernelGGL(k_wcvt, dim3(3072),  dim3(256), 0, stream, Wf, Wb, Wcat);
    hipLaunchKernelGGL(k_wg,   dim3(324),   dim3(256), 0, stream, ne, Wf, Wcat);
    hipLaunchKernelGGL(k_sim,  dim3(81),    dim3(256), 0, stream, sen, S);
    hipLaunchKernelGGL(k_loss, dim3(1),     dim3(128), 0, stream, S, pe, lossp);
    hipLaunchKernelGGL(gemm_main, dim3(3072), dim3(256), 0, stream, x, Wcat, bfv, bbv, bg, bbox, raw, partial);
    hipLaunchKernelGGL(k_fin,  dim3(20736), dim3(256), 0, stream, raw, partial, scores);
}